// Round 8
// baseline (264.438 us; speedup 1.0000x reference)
//
#include <hip/hip_runtime.h>

// R8: barrier-free producer/consumer backlash scan.
// Grid: 128 blocks x 192 threads (3 waves). Block owns 32 rows.
// Wave 0 lanes 0..31: consumer (row = lane). Waves 1-2: producers (16 rows each).
// Chunks of C=32 steps; NTB=3 tile ring; NOB=4 output ring; monotonic LDS
// counters (staged[2], scanned) with cached reads; per-wave in-order DS
// completion makes flag-after-payload ordering safe (protocol proven R7).
// Step math verbatim (bit-exact vs numpy):
//   c1 = (p^s1m) >= L1f ; c2 = ((p^f2m) - a3f) >= a4f
//   p  = c2 ? (c1 ? V11 : V01) : (c1 ? L1 : p)
// LDS strides 33 => bank-quad = (row+step) mod 8; all access phases <=2-way.

#define C 32
#define NCH 64  // T / C
#define NTB 3
#define NOB 4
#define TSP 33  // tile row stride (float4)
#define OSP 33  // ostg/xt row stride (floats)
#define RPB 32  // rows per block

#define CFENCE() asm volatile("" ::: "memory")

__global__ __launch_bounds__(192) void pc_scan(
    const float* __restrict__ x, const float* __restrict__ p0,
    const float4* __restrict__ lstm4, float* __restrict__ out,
    int B, int T) {
#pragma clang fp contract(off)
  __shared__ float4 tileA[NTB][RPB * TSP];  // (s1m, L1f, f2m, a3f)
  __shared__ float4 tileB[NTB][RPB * TSP];  // (a4f, V11, V01, L1)
  __shared__ float xt[RPB * OSP];           // x exchange [row][step]
  __shared__ float ostg[NOB][RPB * OSP];    // outputs [row][step]
  __shared__ int staged[2];                 // per-producer-wave chunk counters
  __shared__ int scanned;                   // consumer chunk counter

  const int tid = threadIdx.x;
  const int b0 = blockIdx.x * RPB;
  const float4* x4 = reinterpret_cast<const float4*>(x);
  float4* out4 = reinterpret_cast<float4*>(out);

  if (tid == 0) { staged[0] = 0; staged[1] = 0; scanned = 0; }
  __syncthreads();

  if (tid >= 64) {
    // ============================ PRODUCERS ============================
    const int pw = (tid >> 6) - 1;  // 0/1
    const int l = tid & 63;
    const int sph = l & 7;                 // step phase / x-quad
    const int lr0 = 16 * pw + (l >> 3);    // local row, j=0
    const int lr1 = lr0 + 8;               // local row, j=1
    const size_t gr0 = (size_t)(b0 + lr0) * T;
    const size_t gr1 = (size_t)(b0 + lr1) * T;

    float4 La0, La1, La2, La3, La4, La5, La6, La7, Xa0, Xa1;
    float4 Lb0, Lb1, Lb2, Lb3, Lb4, Lb5, Lb6, Lb7, Xb0, Xb1;
    int scc = 0;

#define PWAIT(TGT)                                                      \
  if (scc < (TGT)) {                                                    \
    while ((scc = *(volatile int*)&scanned) < (TGT))                    \
      __builtin_amdgcn_s_sleep(1);                                      \
  }                                                                     \
  CFENCE();

#define ISSUE(S, CH)                                                    \
  {                                                                     \
    size_t t0 = (size_t)(CH) * C;                                       \
    const float4* q0 = lstm4 + gr0 + t0 + sph;                          \
    const float4* q1 = lstm4 + gr1 + t0 + sph;                          \
    L##S##0 = q0[0]; L##S##1 = q0[8]; L##S##2 = q0[16]; L##S##3 = q0[24];\
    L##S##4 = q1[0]; L##S##5 = q1[8]; L##S##6 = q1[16]; L##S##7 = q1[24];\
    X##S##0 = x4[((gr0 + t0) >> 2) + sph];                              \
    X##S##1 = x4[((gr1 + t0) >> 2) + sph];                              \
  }

#define STAGE_ELT(LV, LR, SS, SLOT)                                     \
  {                                                                     \
    float4 wv = LV; /* (m_lo, m_up, c_lo, c_up) */                      \
    float xv = xt[(LR)*OSP + (SS)];                                     \
    float a1 = wv.x * xv, a2 = wv.x * wv.z;                             \
    float L1v = a1 + a2;                                                \
    unsigned s1m = __float_as_uint(wv.x) & 0x80000000u;                 \
    float L1f = __uint_as_float(__float_as_uint(L1v) ^ s1m);            \
    float a3 = wv.y * xv, a4 = wv.y * wv.w;                             \
    unsigned f2m = (__float_as_uint(wv.y) & 0x80000000u) ^ 0x80000000u; \
    float a3f = __uint_as_float(__float_as_uint(a3) ^ f2m);             \
    float a4f = __uint_as_float(__float_as_uint(a4) ^ f2m);             \
    float V01 = a3 + a4;                                                \
    float V11 = (L1v + a3) + a4;                                        \
    tileA[SLOT][(LR)*TSP + (SS)] =                                      \
        make_float4(__uint_as_float(s1m), L1f, __uint_as_float(f2m), a3f); \
    tileB[SLOT][(LR)*TSP + (SS)] = make_float4(a4f, V11, V01, L1v);     \
  }

#define STAGE(S, SLOT)                                                  \
  {                                                                     \
    *(float4*)&xt[lr0 * OSP + 4 * sph] = X##S##0;                       \
    *(float4*)&xt[lr1 * OSP + 4 * sph] = X##S##1;                       \
    STAGE_ELT(L##S##0, lr0, sph + 0,  SLOT)                             \
    STAGE_ELT(L##S##1, lr0, sph + 8,  SLOT)                             \
    STAGE_ELT(L##S##2, lr0, sph + 16, SLOT)                             \
    STAGE_ELT(L##S##3, lr0, sph + 24, SLOT)                             \
    STAGE_ELT(L##S##4, lr1, sph + 0,  SLOT)                             \
    STAGE_ELT(L##S##5, lr1, sph + 8,  SLOT)                             \
    STAGE_ELT(L##S##6, lr1, sph + 16, SLOT)                             \
    STAGE_ELT(L##S##7, lr1, sph + 24, SLOT)                             \
  }

#define FLUSH(CP, OB)                                                   \
  {                                                                     \
    float4 v0 = *(const float4*)&ostg[OB][lr0 * OSP + 4 * sph];         \
    float4 v1 = *(const float4*)&ostg[OB][lr1 * OSP + 4 * sph];         \
    size_t t0 = (size_t)(CP) * C;                                       \
    out4[((gr0 + t0) >> 2) + sph] = v0;                                 \
    out4[((gr1 + t0) >> 2) + sph] = v1;                                 \
  }

    ISSUE(a, 0)
    ISSUE(b, 1)

    for (int k = 0; k < NCH; k += 2) {
      PWAIT(k - 2)
      STAGE(a, k % NTB)
      CFENCE();
      if (l == 0) *(volatile int*)&staged[pw] = k + 1;
      if (k + 2 < NCH) ISSUE(a, k + 2)
      if (k >= 3) FLUSH(k - 3, (k - 3) & (NOB - 1))

      PWAIT(k - 1)
      STAGE(b, (k + 1) % NTB)
      CFENCE();
      if (l == 0) *(volatile int*)&staged[pw] = k + 2;
      if (k + 3 < NCH) ISSUE(b, k + 3)
      if (k >= 2) FLUSH(k - 2, (k - 2) & (NOB - 1))
    }
    PWAIT(NCH - 2) FLUSH(NCH - 3, (NCH - 3) & (NOB - 1))
    PWAIT(NCH - 1) FLUSH(NCH - 2, (NCH - 2) & (NOB - 1))
    PWAIT(NCH)     FLUSH(NCH - 1, (NCH - 1) & (NOB - 1))
  } else {
    // ============================ CONSUMER =============================
    float p = (tid < RPB) ? p0[b0 + tid] : 0.0f;
    int st0 = 0, st1 = 0;

#define RSTEP(I, OVC)                                                   \
  {                                                                     \
    float4 A = rA##I;                                                   \
    float4 Bv = rB##I;                                                  \
    if (g < 3) {                                                        \
      rA##I = ta[8 * g + 8 + I];                                        \
      rB##I = tb[8 * g + 8 + I];                                        \
    }                                                                   \
    unsigned pu = __float_as_uint(p);                                   \
    float pf = __uint_as_float(pu ^ __float_as_uint(A.x));              \
    bool c1 = pf >= A.y;                                                \
    float pp = __uint_as_float(pu ^ __float_as_uint(A.z));              \
    float qv = pp - A.w;                                                \
    bool c2 = qv >= Bv.x;                                               \
    float i1 = c1 ? Bv.y : Bv.z;                                        \
    float i2 = c1 ? Bv.w : p;                                           \
    p = c2 ? i1 : i2;                                                   \
    OVC = p;                                                            \
  }

    for (int c = 0; c < NCH; ++c) {
      if (st0 < c + 1 || st1 < c + 1) {
        do {
          st0 = *(volatile int*)&staged[0];
          st1 = *(volatile int*)&staged[1];
        } while (st0 < c + 1 || st1 < c + 1);
      }
      CFENCE();
      {
        const int slot = c % NTB;
        const int ob = c & (NOB - 1);
        if (tid < RPB) {
          const float4* ta = &tileA[slot][tid * TSP];
          const float4* tb = &tileB[slot][tid * TSP];
          float* orow = &ostg[ob][tid * OSP];
          float4 rA0 = ta[0], rA1 = ta[1], rA2 = ta[2], rA3 = ta[3];
          float4 rA4 = ta[4], rA5 = ta[5], rA6 = ta[6], rA7 = ta[7];
          float4 rB0 = tb[0], rB1 = tb[1], rB2 = tb[2], rB3 = tb[3];
          float4 rB4 = tb[4], rB5 = tb[5], rB6 = tb[6], rB7 = tb[7];
#pragma unroll
          for (int g = 0; g < 4; ++g) {
            float4 ov0, ov1;
            RSTEP(0, ov0.x) RSTEP(1, ov0.y) RSTEP(2, ov0.z) RSTEP(3, ov0.w)
            RSTEP(4, ov1.x) RSTEP(5, ov1.y) RSTEP(6, ov1.z) RSTEP(7, ov1.w)
            *(float4*)&orow[8 * g] = ov0;
            *(float4*)&orow[8 * g + 4] = ov1;
          }
        }
      }
      CFENCE();
      if (tid == 0) *(volatile int*)&scanned = c + 1;
    }
  }
}

extern "C" void kernel_launch(void* const* d_in, const int* in_sizes, int n_in,
                              void* d_out, int out_size, void* d_ws, size_t ws_size,
                              hipStream_t stream) {
  const float* x = (const float*)d_in[0];        // (B, T, 1) fp32
  const float* op = (const float*)d_in[1];       // (B, 1, 1) fp32
  const float4* lstm = (const float4*)d_in[2];   // (B, T, 4) fp32
  int B = in_sizes[1];      // 4096
  int T = in_sizes[0] / B;  // 2048
  hipLaunchKernelGGL(pc_scan, dim3(B / RPB), dim3(192), 0, stream,
                     x, op, lstm, (float*)d_out, B, T);
}